// Round 4
// baseline (331.038 us; speedup 1.0000x reference)
//
#include <hip/hip_runtime.h>

// OccGrid batched-dynamic query: nearest-keyframe + 3D occupancy gather.
// R=96, F=16, B=4, N=2e6. 8 queries/thread for 8x gather MLP; vectorized
// streaming I/O (nontemporal) so occ_grid keeps L2/L3 residency.

typedef float f32x4 __attribute__((ext_vector_type(4)));
typedef int   i32x4 __attribute__((ext_vector_type(4)));

__global__ __launch_bounds__(256) void occ_query8_kernel(
    const float* __restrict__ pts,       // (N,3)
    const float* __restrict__ ts,        // (N,)
    const float* __restrict__ occ,       // (B*F, R, R, R)
    const float* __restrict__ kf,        // (F,) sorted
    const int*   __restrict__ bidx,      // (N,)
    float*       __restrict__ out,       // (N,)
    int n)
{
    constexpr int R  = 96;
    constexpr int F  = 16;
    constexpr int R3 = R * R * R;
    constexpr int Q  = 8;                // queries per thread

    float k[F];
#pragma unroll
    for (int j = 0; j < F; ++j) k[j] = kf[j];

    const int tid = blockIdx.x * blockDim.x + threadIdx.x;
    const int i0  = tid * Q;
    if (i0 >= n) return;

    if (i0 + Q <= n) {
        // ---- fast path: 8 consecutive queries, fully vectorized ----
        float pv[24];                    // 8 queries x 3 coords
        const f32x4* p4 = (const f32x4*)pts;
#pragma unroll
        for (int v = 0; v < 6; ++v) {
            const f32x4 x = __builtin_nontemporal_load(&p4[tid * 6 + v]);
            pv[v * 4 + 0] = x.x; pv[v * 4 + 1] = x.y;
            pv[v * 4 + 2] = x.z; pv[v * 4 + 3] = x.w;
        }
        float tt[Q];
        int   bb[Q];
#pragma unroll
        for (int v = 0; v < 2; ++v) {
            const f32x4 t4 = __builtin_nontemporal_load(&((const f32x4*)ts)[tid * 2 + v]);
            const i32x4 b4 = __builtin_nontemporal_load(&((const i32x4*)bidx)[tid * 2 + v]);
            tt[v * 4 + 0] = t4.x; tt[v * 4 + 1] = t4.y;
            tt[v * 4 + 2] = t4.z; tt[v * 4 + 3] = t4.w;
            bb[v * 4 + 0] = b4.x; bb[v * 4 + 1] = b4.y;
            bb[v * 4 + 2] = b4.z; bb[v * 4 + 3] = b4.w;
        }

        int flat[Q];
#pragma unroll
        for (int q = 0; q < Q; ++q) {
            int gx = (int)floorf((pv[q * 3 + 0] * 0.5f + 0.5f) * (float)R);
            int gy = (int)floorf((pv[q * 3 + 1] * 0.5f + 0.5f) * (float)R);
            int gz = (int)floorf((pv[q * 3 + 2] * 0.5f + 0.5f) * (float)R);
            gx = min(max(gx, 0), R - 1);
            gy = min(max(gy, 0), R - 1);
            gz = min(max(gz, 0), R - 1);

            int ins = 0;
#pragma unroll
            for (int j = 0; j < F; ++j) ins += (k[j] < tt[q]) ? 1 : 0;
            const int lo = min(max(ins - 1, 0), F - 1);
            const int hi = min(ins, F - 1);
            const int f  = (fabsf(k[hi] - tt[q]) < fabsf(tt[q] - k[lo])) ? hi : lo;

            flat[q] = (bb[q] * F + f) * R3 + (gx * R + gy) * R + gz;
        }

        // 8 independent gathers issued back-to-back (MLP=8).
        float r[Q];
#pragma unroll
        for (int q = 0; q < Q; ++q) r[q] = occ[flat[q]];

        f32x4 r0 = {r[0], r[1], r[2], r[3]};
        f32x4 r1 = {r[4], r[5], r[6], r[7]};
        __builtin_nontemporal_store(r0, &((f32x4*)out)[tid * 2 + 0]);
        __builtin_nontemporal_store(r1, &((f32x4*)out)[tid * 2 + 1]);
    } else {
        // ---- tail: scalar ----
        for (int i = i0; i < n; ++i) {
            const float px = pts[3 * i + 0];
            const float py = pts[3 * i + 1];
            const float pz = pts[3 * i + 2];
            const float t  = ts[i];
            const int   bq = bidx[i];

            int gx = (int)floorf((px * 0.5f + 0.5f) * (float)R);
            int gy = (int)floorf((py * 0.5f + 0.5f) * (float)R);
            int gz = (int)floorf((pz * 0.5f + 0.5f) * (float)R);
            gx = min(max(gx, 0), R - 1);
            gy = min(max(gy, 0), R - 1);
            gz = min(max(gz, 0), R - 1);

            int ins = 0;
#pragma unroll
            for (int j = 0; j < F; ++j) ins += (k[j] < t) ? 1 : 0;
            const int lo = min(max(ins - 1, 0), F - 1);
            const int hi = min(ins, F - 1);
            const int f  = (fabsf(k[hi] - t) < fabsf(t - k[lo])) ? hi : lo;

            out[i] = occ[(bq * F + f) * R3 + (gx * R + gy) * R + gz];
        }
    }
}

extern "C" void kernel_launch(void* const* d_in, const int* in_sizes, int n_in,
                              void* d_out, int out_size, void* d_ws, size_t ws_size,
                              hipStream_t stream)
{
    const float* pts  = (const float*)d_in[0];
    const float* ts   = (const float*)d_in[1];
    const float* occ  = (const float*)d_in[2];
    const float* kf   = (const float*)d_in[3];
    const int*   bidx = (const int*)d_in[4];
    float* out = (float*)d_out;

    const int n = in_sizes[1];          // ts has N elements
    const int nthreads = (n + 7) / 8;   // 8 queries per thread
    const int blocks = (nthreads + 255) / 256;

    occ_query8_kernel<<<blocks, 256, 0, stream>>>(pts, ts, occ, kf, bidx, out, n);
}